// Round 1
// baseline (243.902 us; speedup 1.0000x reference)
//
#include <hip/hip_runtime.h>
#include <math.h>

#define FEPS 1e-12f

__device__ __forceinline__ float sel8(const float4 a, const float4 b, int idx) {
    float r = a.x;
    r = (idx == 1) ? a.y : r;
    r = (idx == 2) ? a.z : r;
    r = (idx == 3) ? a.w : r;
    r = (idx == 4) ? b.x : r;
    r = (idx == 5) ? b.y : r;
    r = (idx == 6) ? b.z : r;
    r = (idx == 7) ? b.w : r;
    return r;
}

__device__ __forceinline__ float lut_interp(
    float qt, float qc, int arc,
    const float* __restrict__ values,
    const float* __restrict__ trans_tab,
    const float* __restrict__ cap_tab,
    const int* __restrict__ dims)
{
    const int dt = dims[arc * 2 + 0];
    const int dc = dims[arc * 2 + 1];

    const float4* t4 = reinterpret_cast<const float4*>(trans_tab + (size_t)arc * 8);
    const float4 ta = t4[0];
    const float4 tb = t4[1];
    const float4* c4 = reinterpret_cast<const float4*>(cap_tab + (size_t)arc * 8);
    const float4 ca = c4[0];
    const float4 cb = c4[1];

    // searchsorted right=True == count of entries <= query (over all padded T/C)
    int tri = (ta.x <= qt) + (ta.y <= qt) + (ta.z <= qt) + (ta.w <= qt)
            + (tb.x <= qt) + (tb.y <= qt) + (tb.z <= qt) + (tb.w <= qt);
    int cri = (ca.x <= qc) + (ca.y <= qc) + (ca.z <= qc) + (ca.w <= qc)
            + (cb.x <= qc) + (cb.y <= qc) + (cb.z <= qc) + (cb.w <= qc);

    const int max_t = max(dt - 1, 0);
    const int max_c = max(dc - 1, 0);
    const int ti  = min(max(tri, 1), max_t);
    const int ci  = min(max(cri, 1), max_c);
    const int tlo = max(ti - 1, 0);
    const int clo = max(ci - 1, 0);

    const float t0 = sel8(ta, tb, tlo);
    const float t1 = sel8(ta, tb, ti);
    const float c0 = sel8(ca, cb, clo);
    const float c1 = sel8(ca, cb, ci);

    const float* vrow = values + (size_t)arc * 64;
    const float v00 = vrow[tlo * 8 + clo];
    const float v01 = vrow[tlo * 8 + ci];
    const float v10 = vrow[ti * 8 + clo];
    const float v11 = vrow[ti * 8 + ci];

    const float t_int = t1 - t0;
    const float c_int = c1 - c0;
    const bool t_deg = fabsf(t_int) < FEPS;
    const bool c_deg = fabsf(c_int) < FEPS;

    const float x = fminf(fmaxf(qt, t0), t1);
    const float y = fminf(fmaxf(qc, c0), c1);
    const float wa = (t1 - x) * (c1 - y);
    const float wb = (t1 - x) * (y - c0);
    const float wc = (x - t0) * (c1 - y);
    const float wd = (x - t0) * (y - c0);

    const float t_safe = t_deg ? FEPS : t_int;
    const float c_safe = c_deg ? FEPS : c_int;
    const float denom = t_safe * c_safe;

    const float lc = fminf(fmaxf((y - c0) / fmaxf(c_safe, FEPS), 0.0f), 1.0f);
    const float lt = fminf(fmaxf((x - t0) / fmaxf(t_safe, FEPS), 0.0f), 1.0f);
    const float val_t_deg = v00 + lc * (v01 - v00);
    const float val_c_deg = v00 + lt * (v10 - v00);

    const bool valid_den = fabsf(denom) >= FEPS;
    const float denom_s = valid_den ? denom : 1.0f;
    float bil = (v00 * wa + v01 * wb + v10 * wc + v11 * wd) / denom_s;
    bil = (valid_den && isfinite(bil)) ? bil : v00;

    float out = (t_deg && c_deg) ? v00
              : (t_deg ? val_t_deg
              : (c_deg ? val_c_deg : bil));

    const bool valid_arc = (dt > 0) && (dc > 0);
    return (valid_arc && isfinite(out)) ? out : 0.0f;
}

__global__ void __launch_bounds__(256)
TimingPropagation_45329084842413_kernel(
    const float* __restrict__ in_rtrans,
    const float* __restrict__ in_ftrans,
    const float* __restrict__ out_caps,
    const int*   __restrict__ arc_idxs,
    const float* __restrict__ rd_v, const float* __restrict__ rd_t,
    const float* __restrict__ rd_c, const int* __restrict__ rd_d,
    const float* __restrict__ fd_v, const float* __restrict__ fd_t,
    const float* __restrict__ fd_c, const int* __restrict__ fd_d,
    const float* __restrict__ rt_v, const float* __restrict__ rt_t,
    const float* __restrict__ rt_c, const int* __restrict__ rt_d,
    const float* __restrict__ ft_v, const float* __restrict__ ft_t,
    const float* __restrict__ ft_c, const int* __restrict__ ft_d,
    float* __restrict__ out, int n)
{
    const int i = blockIdx.x * blockDim.x + threadIdx.x;
    if (i >= n) return;

    const float qr = in_rtrans[i];
    const float qf = in_ftrans[i];
    const float qc = out_caps[i];
    const int arc = arc_idxs[i];

    out[0 * (size_t)n + i] = lut_interp(qr, qc, arc, rd_v, rd_t, rd_c, rd_d);
    out[1 * (size_t)n + i] = lut_interp(qf, qc, arc, fd_v, fd_t, fd_c, fd_d);
    out[2 * (size_t)n + i] = lut_interp(qr, qc, arc, rt_v, rt_t, rt_c, rt_d);
    out[3 * (size_t)n + i] = lut_interp(qf, qc, arc, ft_v, ft_t, ft_c, ft_d);
}

extern "C" void kernel_launch(void* const* d_in, const int* in_sizes, int n_in,
                              void* d_out, int out_size, void* d_ws, size_t ws_size,
                              hipStream_t stream) {
    const int n = in_sizes[0];

    const float* in_rtrans = (const float*)d_in[0];
    const float* in_ftrans = (const float*)d_in[1];
    const float* out_caps  = (const float*)d_in[2];
    const int*   arc_idxs  = (const int*)d_in[3];

    const float* rd_v = (const float*)d_in[4];
    const float* rd_t = (const float*)d_in[5];
    const float* rd_c = (const float*)d_in[6];
    const int*   rd_d = (const int*)d_in[7];

    const float* fd_v = (const float*)d_in[8];
    const float* fd_t = (const float*)d_in[9];
    const float* fd_c = (const float*)d_in[10];
    const int*   fd_d = (const int*)d_in[11];

    const float* rt_v = (const float*)d_in[12];
    const float* rt_t = (const float*)d_in[13];
    const float* rt_c = (const float*)d_in[14];
    const int*   rt_d = (const int*)d_in[15];

    const float* ft_v = (const float*)d_in[16];
    const float* ft_t = (const float*)d_in[17];
    const float* ft_c = (const float*)d_in[18];
    const int*   ft_d = (const int*)d_in[19];

    float* out = (float*)d_out;

    const int block = 256;
    const int grid = (n + block - 1) / block;
    hipLaunchKernelGGL(TimingPropagation_45329084842413_kernel,
                       dim3(grid), dim3(block), 0, stream,
                       in_rtrans, in_ftrans, out_caps, arc_idxs,
                       rd_v, rd_t, rd_c, rd_d,
                       fd_v, fd_t, fd_c, fd_d,
                       rt_v, rt_t, rt_c, rt_d,
                       ft_v, ft_t, ft_c, ft_d,
                       out, n);
}

// Round 2
// 160.454 us; speedup vs baseline: 1.5201x; 1.5201x over previous
//
#include <hip/hip_runtime.h>
#include <math.h>

#define FEPS 1e-12f
#define LUTL 8192

// d_ws layout
#define QUAD_OFF 0ull                               // 4*L*64*16 B = 33,554,432
#define BP_OFF   33554432ull                        // L*256 B    =  2,097,152
#define DIMS_OFF (33554432ull + 2097152ull)         // L*8 B      =     65,536
#define WS_NEED  (DIMS_OFF + 65536ull)

__device__ __forceinline__ float sel8(const float4 a, const float4 b, int idx) {
    float r = a.x;
    r = (idx == 1) ? a.y : r;
    r = (idx == 2) ? a.z : r;
    r = (idx == 3) ? a.w : r;
    r = (idx == 4) ? b.x : r;
    r = (idx == 5) ? b.y : r;
    r = (idx == 6) ? b.z : r;
    r = (idx == 7) ? b.w : r;
    return r;
}

// ---------------- repack kernel: build quads + breakpoint blocks + packed dims ---------------
__global__ void __launch_bounds__(256)
repack_kernel(const float* __restrict__ rd_v, const float* __restrict__ rd_t,
              const float* __restrict__ rd_c, const int* __restrict__ rd_d,
              const float* __restrict__ fd_v, const float* __restrict__ fd_t,
              const float* __restrict__ fd_c, const int* __restrict__ fd_d,
              const float* __restrict__ rt_v, const float* __restrict__ rt_t,
              const float* __restrict__ rt_c, const int* __restrict__ rt_d,
              const float* __restrict__ ft_v, const float* __restrict__ ft_t,
              const float* __restrict__ ft_c, const int* __restrict__ ft_d,
              float4* __restrict__ quads, float* __restrict__ bp, uint2* __restrict__ dimsp)
{
    const int arc = blockIdx.x;          // 8192 blocks
    const int tid = threadIdx.x;         // 256 threads
    const int lib = tid >> 6;            // wave-uniform: 0..3
    const int q   = tid & 63;            // quad position within row

    const float* v = (lib == 0 ? rd_v : lib == 1 ? fd_v : lib == 2 ? rt_v : ft_v)
                     + (size_t)arc * 64;
    const int t  = q >> 3, c = q & 7;
    const int t1 = min(t + 1, 7), c1 = min(c + 1, 7);
    float4 Q;
    Q.x = v[t * 8 + c];
    Q.y = v[t * 8 + c1];
    Q.z = v[t1 * 8 + c];
    Q.w = v[t1 * 8 + c1];
    quads[((size_t)lib * LUTL + arc) * 64 + q] = Q;

    if (tid < 64) {
        // bp[arc]: 64 floats = per lib {trans[8], cap[8]}
        const int l = tid >> 4, j = tid & 15;
        const float* tt = (l == 0 ? rd_t : l == 1 ? fd_t : l == 2 ? rt_t : ft_t);
        const float* ct = (l == 0 ? rd_c : l == 1 ? fd_c : l == 2 ? rt_c : ft_c);
        const float val = (j < 8) ? tt[(size_t)arc * 8 + j]
                                  : ct[(size_t)arc * 8 + (j - 8)];
        bp[(size_t)arc * 64 + tid] = val;
    } else if (tid == 64) {
        uint2 d;
        d.x = ((unsigned)rd_d[arc * 2] & 0xff) | (((unsigned)rd_d[arc * 2 + 1] & 0xff) << 8)
            | (((unsigned)fd_d[arc * 2] & 0xff) << 16) | (((unsigned)fd_d[arc * 2 + 1] & 0xff) << 24);
        d.y = ((unsigned)rt_d[arc * 2] & 0xff) | (((unsigned)rt_d[arc * 2 + 1] & 0xff) << 8)
            | (((unsigned)ft_d[arc * 2] & 0xff) << 16) | (((unsigned)ft_d[arc * 2 + 1] & 0xff) << 24);
        dimsp[arc] = d;
    }
}

// ---------------- main kernel helpers ----------------
__device__ __forceinline__ void prep(float q, const float4 a, const float4 b, int d,
                                     int& lo, float& x0, float& x1)
{
    const int ri = (a.x <= q) + (a.y <= q) + (a.z <= q) + (a.w <= q)
                 + (b.x <= q) + (b.y <= q) + (b.z <= q) + (b.w <= q);
    const int mx = max(d - 1, 0);
    const int i1 = min(max(ri, 1), mx);
    lo = max(i1 - 1, 0);
    x0 = sel8(a, b, lo);
    x1 = sel8(a, b, i1);
}

__device__ __forceinline__ float finish(float qt, float qc, int dt, int dc,
                                        float t0, float t1, float c0, float c1, float4 v)
{
    const float v00 = v.x, v01 = v.y, v10 = v.z, v11 = v.w;

    const float t_int = t1 - t0;
    const float c_int = c1 - c0;
    const bool t_deg = fabsf(t_int) < FEPS;
    const bool c_deg = fabsf(c_int) < FEPS;

    const float x = fminf(fmaxf(qt, t0), t1);
    const float y = fminf(fmaxf(qc, c0), c1);
    const float wa = (t1 - x) * (c1 - y);
    const float wb = (t1 - x) * (y - c0);
    const float wc = (x - t0) * (c1 - y);
    const float wd = (x - t0) * (y - c0);

    const float t_safe = t_deg ? FEPS : t_int;
    const float c_safe = c_deg ? FEPS : c_int;
    const float denom = t_safe * c_safe;

    const float lc = fminf(fmaxf((y - c0) / fmaxf(c_safe, FEPS), 0.0f), 1.0f);
    const float lt = fminf(fmaxf((x - t0) / fmaxf(t_safe, FEPS), 0.0f), 1.0f);
    const float val_t_deg = v00 + lc * (v01 - v00);
    const float val_c_deg = v00 + lt * (v10 - v00);

    const bool valid_den = fabsf(denom) >= FEPS;
    const float denom_s = valid_den ? denom : 1.0f;
    float bil = (v00 * wa + v01 * wb + v10 * wc + v11 * wd) / denom_s;
    bil = (valid_den && isfinite(bil)) ? bil : v00;

    float out = (t_deg && c_deg) ? v00
              : (t_deg ? val_t_deg
              : (c_deg ? val_c_deg : bil));

    const bool valid_arc = (dt > 0) && (dc > 0);
    return (valid_arc && isfinite(out)) ? out : 0.0f;
}

__global__ void __launch_bounds__(256, 4)
TimingPropagation_45329084842413_kernel(
    const float* __restrict__ in_rtrans,
    const float* __restrict__ in_ftrans,
    const float* __restrict__ out_caps,
    const int*   __restrict__ arc_idxs,
    const float4* __restrict__ bp,
    const uint2*  __restrict__ dimsp,
    const float4* __restrict__ quads,
    float* __restrict__ out, int n)
{
    const int i = blockIdx.x * blockDim.x + threadIdx.x;
    if (i >= n) return;

    const float qr = in_rtrans[i];
    const float qf = in_ftrans[i];
    const float qc = out_caps[i];
    const int arc = arc_idxs[i];

    const uint2 dp = dimsp[arc];
    const int d0t = dp.x & 0xff,         d0c = (dp.x >> 8) & 0xff;
    const int d1t = (dp.x >> 16) & 0xff, d1c = (dp.x >> 24) & 0xff;
    const int d2t = dp.y & 0xff,         d2c = (dp.y >> 8) & 0xff;
    const int d3t = (dp.y >> 16) & 0xff, d3c = (dp.y >> 24) & 0xff;

    const float4* b = bp + (size_t)arc * 16;
    const float4 t0a = b[0],  t0b = b[1],  c0a = b[2],  c0b = b[3];
    const float4 t1a = b[4],  t1b = b[5],  c1a = b[6],  c1b = b[7];
    const float4 t2a = b[8],  t2b = b[9],  c2a = b[10], c2b = b[11];
    const float4 t3a = b[12], t3b = b[13], c3a = b[14], c3b = b[15];

    int lt0, lc0, lt1, lc1, lt2, lc2, lt3, lc3;
    float T00, T01, C00, C01, T10, T11, C10, C11;
    float T20, T21, C20, C21, T30, T31, C30, C31;

    prep(qr, t0a, t0b, d0t, lt0, T00, T01);
    prep(qc, c0a, c0b, d0c, lc0, C00, C01);
    prep(qf, t1a, t1b, d1t, lt1, T10, T11);
    prep(qc, c1a, c1b, d1c, lc1, C10, C11);
    prep(qr, t2a, t2b, d2t, lt2, T20, T21);
    prep(qc, c2a, c2b, d2c, lc2, C20, C21);
    prep(qf, t3a, t3b, d3t, lt3, T30, T31);
    prep(qc, c3a, c3b, d3c, lc3, C30, C31);

    const size_t qb = (size_t)arc * 64;
    const float4 q0 = quads[(size_t)0 * LUTL * 64 + qb + (lt0 * 8 + lc0)];
    const float4 q1 = quads[(size_t)1 * LUTL * 64 + qb + (lt1 * 8 + lc1)];
    const float4 q2 = quads[(size_t)2 * LUTL * 64 + qb + (lt2 * 8 + lc2)];
    const float4 q3 = quads[(size_t)3 * LUTL * 64 + qb + (lt3 * 8 + lc3)];

    out[0 * (size_t)n + i] = finish(qr, qc, d0t, d0c, T00, T01, C00, C01, q0);
    out[1 * (size_t)n + i] = finish(qf, qc, d1t, d1c, T10, T11, C10, C11, q1);
    out[2 * (size_t)n + i] = finish(qr, qc, d2t, d2c, T20, T21, C20, C21, q2);
    out[3 * (size_t)n + i] = finish(qf, qc, d3t, d3c, T30, T31, C30, C31, q3);
}

// ---------------- fallback (round-1 verified kernel) ----------------
__device__ __forceinline__ float lut_interp(
    float qt, float qc, int arc,
    const float* __restrict__ values,
    const float* __restrict__ trans_tab,
    const float* __restrict__ cap_tab,
    const int* __restrict__ dims)
{
    const int dt = dims[arc * 2 + 0];
    const int dc = dims[arc * 2 + 1];

    const float4* t4 = reinterpret_cast<const float4*>(trans_tab + (size_t)arc * 8);
    const float4 ta = t4[0];
    const float4 tb = t4[1];
    const float4* c4 = reinterpret_cast<const float4*>(cap_tab + (size_t)arc * 8);
    const float4 ca = c4[0];
    const float4 cb = c4[1];

    int lo_t, lo_c; float t0, t1, c0, c1;
    prep(qt, ta, tb, dt, lo_t, t0, t1);
    prep(qc, ca, cb, dc, lo_c, c0, c1);
    const int ti = min(max(lo_t + 1, 0), max(dt - 1, 0));
    const int ci = min(max(lo_c + 1, 0), max(dc - 1, 0));
    // reconstruct exact indices as in reference
    const int tlo = lo_t, clo = lo_c;

    const float* vrow = values + (size_t)arc * 64;
    float4 v;
    v.x = vrow[tlo * 8 + clo];
    v.y = vrow[tlo * 8 + ci];
    v.z = vrow[ti * 8 + clo];
    v.w = vrow[ti * 8 + ci];
    return finish(qt, qc, dt, dc, t0, t1, c0, c1, v);
}

__global__ void __launch_bounds__(256)
fallback_kernel(
    const float* __restrict__ in_rtrans,
    const float* __restrict__ in_ftrans,
    const float* __restrict__ out_caps,
    const int*   __restrict__ arc_idxs,
    const float* __restrict__ rd_v, const float* __restrict__ rd_t,
    const float* __restrict__ rd_c, const int* __restrict__ rd_d,
    const float* __restrict__ fd_v, const float* __restrict__ fd_t,
    const float* __restrict__ fd_c, const int* __restrict__ fd_d,
    const float* __restrict__ rt_v, const float* __restrict__ rt_t,
    const float* __restrict__ rt_c, const int* __restrict__ rt_d,
    const float* __restrict__ ft_v, const float* __restrict__ ft_t,
    const float* __restrict__ ft_c, const int* __restrict__ ft_d,
    float* __restrict__ out, int n)
{
    const int i = blockIdx.x * blockDim.x + threadIdx.x;
    if (i >= n) return;
    const float qr = in_rtrans[i];
    const float qf = in_ftrans[i];
    const float qc = out_caps[i];
    const int arc = arc_idxs[i];
    out[0 * (size_t)n + i] = lut_interp(qr, qc, arc, rd_v, rd_t, rd_c, rd_d);
    out[1 * (size_t)n + i] = lut_interp(qf, qc, arc, fd_v, fd_t, fd_c, fd_d);
    out[2 * (size_t)n + i] = lut_interp(qr, qc, arc, rt_v, rt_t, rt_c, rt_d);
    out[3 * (size_t)n + i] = lut_interp(qf, qc, arc, ft_v, ft_t, ft_c, ft_d);
}

extern "C" void kernel_launch(void* const* d_in, const int* in_sizes, int n_in,
                              void* d_out, int out_size, void* d_ws, size_t ws_size,
                              hipStream_t stream) {
    const int n = in_sizes[0];

    const float* in_rtrans = (const float*)d_in[0];
    const float* in_ftrans = (const float*)d_in[1];
    const float* out_caps  = (const float*)d_in[2];
    const int*   arc_idxs  = (const int*)d_in[3];

    const float* rd_v = (const float*)d_in[4];
    const float* rd_t = (const float*)d_in[5];
    const float* rd_c = (const float*)d_in[6];
    const int*   rd_d = (const int*)d_in[7];

    const float* fd_v = (const float*)d_in[8];
    const float* fd_t = (const float*)d_in[9];
    const float* fd_c = (const float*)d_in[10];
    const int*   fd_d = (const int*)d_in[11];

    const float* rt_v = (const float*)d_in[12];
    const float* rt_t = (const float*)d_in[13];
    const float* rt_c = (const float*)d_in[14];
    const int*   rt_d = (const int*)d_in[15];

    const float* ft_v = (const float*)d_in[16];
    const float* ft_t = (const float*)d_in[17];
    const float* ft_c = (const float*)d_in[18];
    const int*   ft_d = (const int*)d_in[19];

    float* out = (float*)d_out;
    const int block = 256;
    const int grid = (n + block - 1) / block;

    if (ws_size >= WS_NEED) {
        char* ws = (char*)d_ws;
        float4* quads = (float4*)(ws + QUAD_OFF);
        float*  bpf   = (float*)(ws + BP_OFF);
        uint2*  dimsp = (uint2*)(ws + DIMS_OFF);

        hipLaunchKernelGGL(repack_kernel, dim3(LUTL), dim3(256), 0, stream,
                           rd_v, rd_t, rd_c, rd_d,
                           fd_v, fd_t, fd_c, fd_d,
                           rt_v, rt_t, rt_c, rt_d,
                           ft_v, ft_t, ft_c, ft_d,
                           quads, bpf, dimsp);

        hipLaunchKernelGGL(TimingPropagation_45329084842413_kernel,
                           dim3(grid), dim3(block), 0, stream,
                           in_rtrans, in_ftrans, out_caps, arc_idxs,
                           (const float4*)bpf, (const uint2*)dimsp,
                           (const float4*)quads, out, n);
    } else {
        hipLaunchKernelGGL(fallback_kernel,
                           dim3(grid), dim3(block), 0, stream,
                           in_rtrans, in_ftrans, out_caps, arc_idxs,
                           rd_v, rd_t, rd_c, rd_d,
                           fd_v, fd_t, fd_c, fd_d,
                           rt_v, rt_t, rt_c, rt_d,
                           ft_v, ft_t, ft_c, ft_d,
                           out, n);
    }
}